// Round 1
// baseline (317.642 us; speedup 1.0000x reference)
//
#include <hip/hip_runtime.h>
#include <stdint.h>

typedef unsigned long long u64;
typedef unsigned int u32;

#define FH 37
#define FW 62
#define NA 9
#define NPRED (FH*FW*NA)   // 20646
#define BS 4
#define KEEP_PRE 6000
#define KEEP_POST 300
#define NWORDS 94          // ceil(6000/64)
#define NBINS 4096
#define GSZ 16

// ws layout (bytes), all 16B aligned
#define OFF_KEYS    0u
#define OFF_BOXES   660672u
#define OFF_HIST    1982016u
#define OFF_SUFFIX  2047552u
#define OFF_CURSOR  2113088u
#define OFF_SORTED  2178624u
#define OFF_PROPS   2839296u
#define OFF_CONF    3223296u
#define OFF_LIST    3319296u
#define OFF_COUNTS  3324096u
#define OFF_MASK    3324112u
#define WS_NEEDED   21372112u

// ---------------------------------------------------------------------------
// Kernel 1: keys (order-exact sort key from pred bits) + box decode + histogram
// ---------------------------------------------------------------------------
__global__ void __launch_bounds__(1024) prep_kernel(
    const float* __restrict__ preds, const float* __restrict__ regs,
    const int* __restrict__ ih, const int* __restrict__ iw,
    u64* __restrict__ keys, float4* __restrict__ boxes, u32* __restrict__ ghist)
{
  __shared__ u32 lh[NBINS];
  const int tid = threadIdx.x;
  const int b = blockIdx.y;
  for (int v = tid; v < NBINS; v += 1024) lh[v] = 0;
  __syncthreads();
  const int n = blockIdx.x * 1024 + tid;
  if (n < NPRED) {
    float p = preds[b*NPRED + n];
    u32 u = __float_as_uint(p);
    u32 m = (u & 0x80000000u) ? ~u : (u | 0x80000000u);  // order-preserving map
    u64 key = ((u64)m << 32) | (u32)(~(u32)n);           // tiebreak: lower idx first
    keys[b*NPRED + n] = key;
    atomicAdd(&lh[m >> 20], 1u);

    // decode box, mirroring reference op order
    int a = n % NA;
    int cell = n / NA;
    int x = cell % FW;
    int y = cell / FW;
    int si = a % 3, ri = a / 3;
    float s = (si==0) ? 8.f : ((si==1) ? 16.f : 32.f);
    float r = (ri==0) ? 0.5f : ((ri==1) ? 1.0f : 2.0f);
    float aw = s * sqrtf(1.0f / r);
    float ah = s * sqrtf(r);
    float gx = (float)x * 16.f, gy = (float)y * 16.f;
    float x1d = gx - 0.5f*aw, x2d = gx + 0.5f*aw;
    float y1d = gy - 0.5f*ah, y2d = gy + 0.5f*ah;
    float w = x2d - x1d, h = y2d - y1d;
    float cx = x1d + 0.5f*w, cy = y1d + 0.5f*h;
    float4 d = reinterpret_cast<const float4*>(regs)[b*NPRED + n];
    float pcx = d.x*w + cx, pcy = d.y*h + cy;
    float pw = expf(d.z)*w, ph = expf(d.w)*h;
    float W = (float)(*iw), H = (float)(*ih);
    float bx1 = fminf(fmaxf(pcx - 0.5f*pw, 0.f), W);
    float by1 = fminf(fmaxf(pcy - 0.5f*ph, 0.f), H);
    float bx2 = fminf(fmaxf(pcx + 0.5f*pw, 0.f), W);
    float by2 = fminf(fmaxf(pcy + 0.5f*ph, 0.f), H);
    boxes[b*NPRED + n] = make_float4(bx1, by1, bx2, by2);
  }
  __syncthreads();
  for (int v = tid; v < NBINS; v += 1024) {
    u32 c = lh[v];
    if (c) atomicAdd(&ghist[b*NBINS + v], c);
  }
}

// ---------------------------------------------------------------------------
// Kernel 2: per-batch suffix sum over bins (count of elements in higher bins)
// ---------------------------------------------------------------------------
__global__ void __launch_bounds__(1024) suffix_kernel(
    const u32* __restrict__ ghist, u32* __restrict__ gsuffix, u32* __restrict__ gcursor)
{
  __shared__ u32 vals[NBINS];
  __shared__ u32 psum[1024];
  const int b = blockIdx.x, t = threadIdx.x;
  for (int v = t; v < NBINS; v += 1024) vals[v] = ghist[b*NBINS + v];
  __syncthreads();
  u32 a0 = vals[4*t], a1 = vals[4*t+1], a2 = vals[4*t+2], a3 = vals[4*t+3];
  u32 s = a0 + a1 + a2 + a3;
  psum[t] = s;
  __syncthreads();
  for (int off = 1; off < 1024; off <<= 1) {
    u32 add = (t + off < 1024) ? psum[t + off] : 0;
    __syncthreads();
    psum[t] += add;
    __syncthreads();
  }
  u32 tail = psum[t] - s;        // sum over threads > t
  u32 s3 = tail;
  u32 s2 = s3 + a3;
  u32 s1 = s2 + a2;
  u32 s0 = s1 + a1;
  int base = b*NBINS + 4*t;
  gsuffix[base+0]=s0; gsuffix[base+1]=s1; gsuffix[base+2]=s2; gsuffix[base+3]=s3;
  gcursor[base+0]=s0; gcursor[base+1]=s1; gcursor[base+2]=s2; gcursor[base+3]=s3;
}

// ---------------------------------------------------------------------------
// Kernel 3: scatter keys into bin-ordered array (counting sort, order within
// bin irrelevant — exact rank computed by comparison later)
// ---------------------------------------------------------------------------
__global__ void __launch_bounds__(1024) scatter_kernel(
    const u64* __restrict__ keys, u32* __restrict__ gcursor, u64* __restrict__ sorted)
{
  const int b = blockIdx.y;
  const int n = blockIdx.x*1024 + threadIdx.x;
  if (n >= NPRED) return;
  u64 k = keys[b*NPRED + n];
  u32 bin = (u32)(k >> 52);
  u32 pos = atomicAdd(&gcursor[b*NBINS + bin], 1u);
  sorted[b*NPRED + pos] = k;
}

// ---------------------------------------------------------------------------
// Kernel 4: exact rank (bin base + in-bin count of larger keys); gather props
// ---------------------------------------------------------------------------
__global__ void __launch_bounds__(1024) rank_kernel(
    const u64* __restrict__ sorted, const u32* __restrict__ gsuffix,
    const u32* __restrict__ ghist, const float4* __restrict__ boxes,
    float4* __restrict__ props, u32* __restrict__ conf)
{
  const int b = blockIdx.y;
  const int p = blockIdx.x*1024 + threadIdx.x;
  if (p >= NPRED) return;
  u64 k = sorted[b*NPRED + p];
  u32 bin = (u32)(k >> 52);
  u32 base = gsuffix[b*NBINS + bin];
  if (base >= KEEP_PRE) return;              // definitely not in top-6000
  u32 cnt = ghist[b*NBINS + bin];
  u32 r = base;
  const u64* sb = sorted + b*NPRED;
  for (u32 q = base; q < base + cnt; ++q) r += (sb[q] > k) ? 1u : 0u;
  if (r < KEEP_PRE) {
    u32 idx = ~(u32)k;
    props[b*KEEP_PRE + r] = boxes[b*NPRED + idx];
    conf[b*KEEP_PRE + r] = (u32)(k >> 63);   // pred>0 <=> sigmoid>0.5
  }
}

// ---------------------------------------------------------------------------
// Kernel 5: suppression bitmask: mask[b][i][cb] bit jj = (j>i && IoU>0.7)
// ---------------------------------------------------------------------------
__global__ void __launch_bounds__(64) mask_kernel(
    const float4* __restrict__ props, u64* __restrict__ mask)
{
  const int cb = blockIdx.x, rb = blockIdx.y, b = blockIdx.z;
  const int t = threadIdx.x;
  __shared__ float4 cbox[64];
  __shared__ float carea[64];
  int j0 = cb*64 + t;
  float4 bj = make_float4(0.f, 0.f, 0.f, 0.f);
  if (j0 < KEEP_PRE) bj = props[b*KEEP_PRE + j0];
  cbox[t] = bj;
  carea[t] = fmaxf(bj.z - bj.x, 0.f) * fmaxf(bj.w - bj.y, 0.f);
  __syncthreads();
  const int i = rb*64 + t;
  if (i >= KEEP_PRE) return;
  u64 word = 0;
  if (cb*64 + 63 > i) {   // block contains some j > i
    float4 bi = props[b*KEEP_PRE + i];
    float ai = fmaxf(bi.z - bi.x, 0.f) * fmaxf(bi.w - bi.y, 0.f);
    for (int jj = 0; jj < 64; ++jj) {
      int j = cb*64 + jj;
      float4 bb = cbox[jj];
      float ltx = fmaxf(bi.x, bb.x), lty = fmaxf(bi.y, bb.y);
      float rbx = fminf(bi.z, bb.z), rby = fminf(bi.w, bb.w);
      float wx = fmaxf(rbx - ltx, 0.f), wy = fmaxf(rby - lty, 0.f);
      float inter = wx * wy;
      float un = ai + carea[jj] - inter;
      bool sup = (j > i) && (j < KEEP_PRE) && (inter > 0.7f * fmaxf(un, 1e-9f));
      word |= ((u64)(sup ? 1u : 0u)) << jj;
    }
  }
  mask[((size_t)(b*KEEP_PRE) + i)*NWORDS + cb] = word;
}

// ---------------------------------------------------------------------------
// Kernel 6: serial greedy sweep per batch (94-word keep bitmap in LDS),
// double-buffered 16-row mask prefetch, early exit at 300 kept
// ---------------------------------------------------------------------------
__global__ void __launch_bounds__(128) sweep_kernel(
    const u64* __restrict__ mask, int* __restrict__ listg, int* __restrict__ counts)
{
  const int b = blockIdx.x, tid = threadIdx.x;
  __shared__ u64 keepw[NWORDS];
  __shared__ int list[KEEP_POST];
  __shared__ int cnt;
  if (tid < NWORDS) keepw[tid] = (tid == NWORDS-1) ? ((1ull << 48) - 1ull) : ~0ull;
  if (tid == 0) cnt = 0;
  __syncthreads();
  const u64* mb = mask + (size_t)b * KEEP_PRE * NWORDS;

  u64 bufA[GSZ], bufB[GSZ];

  // NB: mask row i never has bit i set (j>i strict), so a cross-wave racy read
  // of keepw[i>>6] concurrent with this iteration's AND still yields the same
  // bit-i decision on every wave -> barrier convergence holds.
  auto process = [&](u64 (&buf)[GSZ], int gb) -> bool {
    #pragma unroll
    for (int rr = 0; rr < GSZ; ++rr) {
      int i = gb + rr;
      if (i >= KEEP_PRE) return true;
      u64 kw = keepw[i >> 6];
      if ((kw >> (i & 63)) & 1ull) {
        if (tid == 0) { list[cnt] = i; cnt = cnt + 1; }
        if (tid < NWORDS) keepw[tid] &= ~buf[rr];
        __syncthreads();
        if (cnt >= KEEP_POST) return true;
      }
    }
    return false;
  };

  #pragma unroll
  for (int rr = 0; rr < GSZ; ++rr)
    bufA[rr] = (tid < NWORDS) ? mb[(size_t)rr * NWORDS + tid] : 0ull;

  int gbase = 0;
  for (;;) {
    #pragma unroll
    for (int rr = 0; rr < GSZ; ++rr) {
      int i = gbase + GSZ + rr;
      bufB[rr] = (tid < NWORDS && i < KEEP_PRE) ? mb[(size_t)i * NWORDS + tid] : 0ull;
    }
    if (process(bufA, gbase)) break;
    gbase += GSZ;
    #pragma unroll
    for (int rr = 0; rr < GSZ; ++rr) {
      int i = gbase + GSZ + rr;
      bufA[rr] = (tid < NWORDS && i < KEEP_PRE) ? mb[(size_t)i * NWORDS + tid] : 0ull;
    }
    if (process(bufB, gbase)) break;
    gbase += GSZ;
  }

  __syncthreads();
  if (tid == 0) counts[b] = cnt;
  for (int k = tid; k < KEEP_POST; k += 128)
    listg[b*KEEP_POST + k] = (k < cnt) ? list[k] : -1;
}

// ---------------------------------------------------------------------------
// Kernel 7: write output rows (first 300 kept, conf-filtered, rest zero)
// ---------------------------------------------------------------------------
__global__ void __launch_bounds__(512) finalize_kernel(
    const float4* __restrict__ props, const u32* __restrict__ conf,
    const int* __restrict__ listg, const int* __restrict__ counts,
    float4* __restrict__ out)
{
  const int b = blockIdx.x;
  const int k = threadIdx.x;
  if (k >= KEEP_POST) return;
  int c = counts[b];
  float4 o = make_float4(0.f, 0.f, 0.f, 0.f);
  if (k < c) {
    int r = listg[b*KEEP_POST + k];
    if (conf[b*KEEP_PRE + r]) o = props[b*KEEP_PRE + r];
  }
  out[b*KEEP_POST + k] = o;
}

extern "C" void kernel_launch(void* const* d_in, const int* in_sizes, int n_in,
                              void* d_out, int out_size, void* d_ws, size_t ws_size,
                              hipStream_t stream) {
  const float* preds = (const float*)d_in[0];
  const float* regs  = (const float*)d_in[1];
  const int* ih      = (const int*)d_in[2];
  const int* iw      = (const int*)d_in[3];

  if (ws_size < (size_t)WS_NEEDED) return;  // loud failure (poisoned out)

  char* ws = (char*)d_ws;
  u64*    keys    = (u64*)   (ws + OFF_KEYS);
  float4* boxes   = (float4*)(ws + OFF_BOXES);
  u32*    ghist   = (u32*)   (ws + OFF_HIST);
  u32*    gsuffix = (u32*)   (ws + OFF_SUFFIX);
  u32*    gcursor = (u32*)   (ws + OFF_CURSOR);
  u64*    sorted  = (u64*)   (ws + OFF_SORTED);
  float4* props   = (float4*)(ws + OFF_PROPS);
  u32*    conf    = (u32*)   (ws + OFF_CONF);
  int*    listg   = (int*)   (ws + OFF_LIST);
  int*    counts  = (int*)   (ws + OFF_COUNTS);
  u64*    mask    = (u64*)   (ws + OFF_MASK);

  hipMemsetAsync(ghist, 0, BS*NBINS*sizeof(u32), stream);

  dim3 g21((NPRED + 1023)/1024, BS);   // (21, 4)
  prep_kernel<<<g21, 1024, 0, stream>>>(preds, regs, ih, iw, keys, boxes, ghist);
  suffix_kernel<<<dim3(BS), 1024, 0, stream>>>(ghist, gsuffix, gcursor);
  scatter_kernel<<<g21, 1024, 0, stream>>>(keys, gcursor, sorted);
  rank_kernel<<<g21, 1024, 0, stream>>>(sorted, gsuffix, ghist, boxes, props, conf);
  mask_kernel<<<dim3(NWORDS, NWORDS, BS), 64, 0, stream>>>(props, mask);
  sweep_kernel<<<dim3(BS), 128, 0, stream>>>(mask, listg, counts);
  finalize_kernel<<<dim3(BS), 512, 0, stream>>>(props, conf, listg, counts, (float4*)d_out);
}